// Round 6
// baseline (1187.444 us; speedup 1.0000x reference)
//
#include <hip/hip_runtime.h>
#include <hip/hip_bf16.h>
#include <math.h>

#define TPTS 96
#define CTOT 128

typedef __bf16 bf16x8_t __attribute__((ext_vector_type(8)));
typedef float f32x4_t __attribute__((ext_vector_type(4)));
typedef unsigned short us8_t __attribute__((ext_vector_type(8)));

__device__ __forceinline__ unsigned short f2b(float f) {
    union { float f; unsigned int i; } v; v.f = f;
    unsigned int r = v.i + 0x7fffu + ((v.i >> 16) & 1u);
    return (unsigned short)(r >> 16);
}
__device__ __forceinline__ unsigned int packbf2(float a, float b) {
    unsigned int r;
    asm("v_cvt_pk_bf16_f32 %0, %1, %2" : "=v"(r) : "v"(a), "v"(b));
    return r;
}
__device__ __forceinline__ uint2 pack4(float v0, float v1, float v2, float v3) {
    uint2 w; w.x = packbf2(v0, v1); w.y = packbf2(v2, v3); return w;
}
__device__ __forceinline__ f32x4_t mfma16(bf16x8_t a, bf16x8_t b, f32x4_t c) {
    return __builtin_amdgcn_mfma_f32_16x16x32_bf16(a, b, c, 0, 0, 0);
}
__device__ __forceinline__ bf16x8_t ldfrag(const unsigned short* p) {
    us8_t v = *(const us8_t*)p;
    return __builtin_bit_cast(bf16x8_t, v);
}
// Cross-XCD coherent fragment load (relaxed agent atomics -> LLC)
__device__ __forceinline__ bf16x8_t ldfragG(const unsigned short* p) {
    union { unsigned long long q[2]; us8_t v; } u;
    u.q[0] = __hip_atomic_load((const unsigned long long*)p,
                               __ATOMIC_RELAXED, __HIP_MEMORY_SCOPE_AGENT);
    u.q[1] = __hip_atomic_load((const unsigned long long*)(p + 4),
                               __ATOMIC_RELAXED, __HIP_MEMORY_SCOPE_AGENT);
    return __builtin_bit_cast(bf16x8_t, u.v);
}
// Cross-XCD coherent 8B store: write-through to LLC.
__device__ __forceinline__ void stg8(unsigned short* p, uint2 pk) {
    unsigned long long q = ((unsigned long long)pk.y << 32) | (unsigned long long)pk.x;
    __hip_atomic_store((unsigned long long*)p, q,
                       __ATOMIC_RELAXED, __HIP_MEMORY_SCOPE_AGENT);
}
__device__ __forceinline__ bf16x8_t ldfragW(const float* p) {
    float4 a = *(const float4*)p;
    float4 b = *(const float4*)(p + 4);
    bf16x8_t r;
    r[0] = __builtin_bit_cast(__bf16, f2b(a.x)); r[1] = __builtin_bit_cast(__bf16, f2b(a.y));
    r[2] = __builtin_bit_cast(__bf16, f2b(a.z)); r[3] = __builtin_bit_cast(__bf16, f2b(a.w));
    r[4] = __builtin_bit_cast(__bf16, f2b(b.x)); r[5] = __builtin_bit_cast(__bf16, f2b(b.y));
    r[6] = __builtin_bit_cast(__bf16, f2b(b.z)); r[7] = __builtin_bit_cast(__bf16, f2b(b.w));
    return r;
}
__device__ __forceinline__ float tanh2(float x) {   // finite inputs only
    float e = __expf(x + x);
    return 1.f - __fdividef(2.f, e + 1.f);
}
#define TWO_LOG2E 2.8853900817779268f
__device__ __forceinline__ float tanhfast(float acc, float bl) {
    float e = __builtin_amdgcn_exp2f(fmaf(acc, TWO_LOG2E, bl));  // exp(2(acc+bo))
    float r = __builtin_amdgcn_rcpf(e + 1.f);
    return fmaf(-2.f, r, 1.f);
}
__device__ __forceinline__ float sigm(float x) {
    return __fdividef(1.f, 1.f + __expf(-x));
}

#define LGKM_BAR() do {                                         \
        asm volatile("s_waitcnt lgkmcnt(0)" ::: "memory");      \
        __builtin_amdgcn_s_barrier();                           \
    } while (0)

__device__ __forceinline__ void waitflag(unsigned int* f, unsigned int want) {
    if (threadIdx.x == 0) {
        int guard = 0;
        while (__hip_atomic_load(f, __ATOMIC_RELAXED, __HIP_MEMORY_SCOPE_AGENT) != want) {
            __builtin_amdgcn_s_sleep(8);   // coarse poll: cut LLC poll-storm
            if (++guard > (1 << 19)) break;   // hang-proof: degrade, don't wedge
        }
    }
    __syncthreads();
}

// R10: 128 blocks x 1024 thr (16 waves).
// Block type A (blockIdx<64): ODE producer (waves 0-7, R2-proven math, wode in
//   regs) + GRU0 (waves 8-15) FUSED. y handoff via LDS ybuf (double-buffered by
//   step parity) -- NO yTraj stores, NO yflag, NO polling. Unified rhythm:
//   both roles execute exactly 6 LGKM_BARs per step in barrier-matched loops.
//   Only remaining LLC handoff: h1 -> block B (+h1flag, released 1 step late
//   after each wave's own vmcnt drain + a barrier).
// Block type B (blockIdx>=64): GRU1 (waves 0-7) + MLP head; waves 8-15 ride
//   along hitting every sync (weight loads guarded to avoid OOB).
// Theory: the 683us plateau was LLC poll-storm contention on the flag/data
//   fabric; this removes 2 of 3 handoffs and 95% of poll traffic.
__global__ void __launch_bounds__(1024, 1)
ode_forecaster(const float* __restrict__ yl,
               const float* __restrict__ yh,
               const float* __restrict__ Wode,
               const float* __restrict__ bode,
               const float* __restrict__ Wih0,
               const float* __restrict__ Whh0,
               const float* __restrict__ bih0,
               const float* __restrict__ bhh0,
               const float* __restrict__ Wih1,
               const float* __restrict__ Whh1,
               const float* __restrict__ bih1,
               const float* __restrict__ bhh1,
               const float* __restrict__ W1v,
               const float* __restrict__ b1v,
               const float* __restrict__ W2v,
               const float* __restrict__ b2v,
               float* __restrict__ outp,
               char* __restrict__ wsb)
{
    const int btype = blockIdx.x >> 6;
    const int c     = blockIdx.x & 63;
    const int tid   = threadIdx.x, lane = tid & 63, wv = tid >> 6;
    const int l15   = lane & 15, quad = lane >> 4;
    const int gw    = wv & 7;
    const int fb    = gw * 16 + quad * 4;
    const int rbase = c * 16;
    const int row   = rbase + l15;

    __shared__ __align__(16) char smem[25728];

    unsigned short* h1Traj = (unsigned short*)(wsb + 0x2000000);
    unsigned int*   h1flag = (unsigned int*)(wsb + 0x4010000);
#define H1MAGIC(t) (0x6E000000u + (unsigned)(t))

    if (btype == 0) {
        // ============== Block A: ODE producer + GRU0, LDS-fused ==============
        unsigned short (*zb)[16][134]   = (unsigned short (*)[16][134])(smem);           // [2][16][134]
        unsigned short (*ybuf)[16][134] = (unsigned short (*)[16][134])(smem + 8576);    // [2][16][134]
        unsigned short (*hb)[16][134]   = (unsigned short (*)[16][134])(smem + 17152);   // [2][16][134]

        if (wv < 8) {
            // ---------------- producer waves ----------------
            bf16x8_t wode[4];
#pragma unroll
            for (int kt = 0; kt < 4; ++kt)
                wode[kt] = ldfragW(Wode + (gw * 16 + l15) * CTOT + kt * 32 + quad * 8);
            float bl[4];
            {
                float4 b4 = *(const float4*)(bode + fb);
                bl[0] = b4.x * TWO_LOG2E; bl[1] = b4.y * TWO_LOG2E;
                bl[2] = b4.z * TWO_LOG2E; bl[3] = b4.w * TWO_LOG2E;
            }
            float y[4], yn[4], kr[4][4];
#pragma unroll
            for (int i = 0; i < 4; ++i) {
                int f = fb + i;
                y[i] = (f < 32) ? yl[row * 32 + f] : yh[row * 96 + (f - 32)];
            }
            {
                uint2 pk = pack4(y[0], y[1], y[2], y[3]);
                *(uint2*)&zb[0][l15][fb] = pk;
                *(uint2*)&ybuf[0][l15][fb] = pk;
            }
            __syncthreads();   // setup barrier (matched below)

            const float dt = 1.0f / 95.0f;
            const float d10 = dt * 0.2f;
            const float d20 = dt * (3.f/40.f),  d21 = dt * (9.f/40.f);
            const float d30 = dt * (44.f/45.f), d31 = dt * (-56.f/15.f), d32 = dt * (32.f/9.f);
            const float d40 = dt * (19372.f/6561.f), d41 = dt * (-25360.f/2187.f),
                        d42 = dt * (64448.f/6561.f), d43 = dt * (-212.f/729.f);
            const float d50 = dt * (9017.f/3168.f), d51 = dt * (-355.f/33.f),
                        d52 = dt * (46732.f/5247.f), d53 = dt * (49.f/176.f),
                        d54 = dt * (-5103.f/18656.f);
            const float e0 = dt * (35.f/384.f), e2 = dt * (500.f/1113.f), e3 = dt * (125.f/192.f),
                        e4 = dt * (-2187.f/6784.f), e5 = dt * (11.f/84.f);

            int p = 0;
#pragma unroll 1
            for (int T = 0; T <= 96; ++T) {
#pragma unroll
                for (int s = 0; s < 6; ++s) {
                    if (T < 95) {
                        bf16x8_t zf[4];
#pragma unroll
                        for (int kt = 0; kt < 4; ++kt)
                            zf[kt] = ldfrag(&zb[p][l15][kt * 32 + quad * 8]);
                        const f32x4_t zz4 = {0.f, 0.f, 0.f, 0.f};
                        f32x4_t a0 = mfma16(wode[0], zf[0], zz4);
                        f32x4_t a1 = mfma16(wode[1], zf[1], zz4);
                        f32x4_t a2 = mfma16(wode[2], zf[2], zz4);
                        f32x4_t a3 = mfma16(wode[3], zf[3], zz4);
                        f32x4_t acc = (a0 + a1) + (a2 + a3);
                        float kf[4];
#pragma unroll
                        for (int i = 0; i < 4; ++i) kf[i] = tanhfast(acc[i], bl[i]);
                        if (s < 4)
#pragma unroll
                            for (int i = 0; i < 4; ++i) kr[s][i] = kf[i];
#pragma unroll
                        for (int i = 0; i < 4; ++i) {
                            if (s == 0)      yn[i] = fmaf(e0, kf[i], y[i]);
                            else if (s == 2) yn[i] = fmaf(e2, kf[i], yn[i]);
                            else if (s == 3) yn[i] = fmaf(e3, kf[i], yn[i]);
                            else if (s == 4) yn[i] = fmaf(e4, kf[i], yn[i]);
                            else if (s == 5) y[i]  = fmaf(e5, kf[i], yn[i]);
                        }
                        float zv[4];
#pragma unroll
                        for (int i = 0; i < 4; ++i) {
                            float zvv;
                            if (s == 0)      zvv = fmaf(d10, kf[i], y[i]);
                            else if (s == 1) zvv = fmaf(d21, kf[i],
                                                    fmaf(d20, kr[0][i], y[i]));
                            else if (s == 2) zvv = fmaf(d32, kf[i],
                                                    fmaf(d31, kr[1][i],
                                                    fmaf(d30, kr[0][i], y[i])));
                            else if (s == 3) zvv = fmaf(d43, kf[i],
                                                    fmaf(d42, kr[2][i],
                                                    fmaf(d41, kr[1][i],
                                                    fmaf(d40, kr[0][i], y[i]))));
                            else if (s == 4) zvv = fmaf(d54, kf[i],
                                                    fmaf(d53, kr[3][i],
                                                    fmaf(d52, kr[2][i],
                                                    fmaf(d51, kr[1][i],
                                                    fmaf(d50, kr[0][i], y[i])))));
                            else             zvv = y[i];   // s==5: z_next = y_{T+1}
                            zv[i] = zvv;
                        }
                        uint2 pk = pack4(zv[0], zv[1], zv[2], zv[3]);
                        *(uint2*)&zb[p ^ 1][l15][fb] = pk;
                        if (s == 5)
                            *(uint2*)&ybuf[(T + 1) & 1][l15][fb] = pk;   // y[T+1] for GRU0
                    }
                    LGKM_BAR();
                    p ^= 1;
                }
            }
        } else {
            // ---------------- GRU0 waves ----------------
            bf16x8_t wih[3][4], whh[3][4];
#pragma unroll
            for (int g = 0; g < 3; ++g)
#pragma unroll
                for (int kt = 0; kt < 4; ++kt) {
                    wih[g][kt] = ldfragW(Wih0 + (size_t)(g * 128 + gw * 16 + l15) * CTOT + kt * 32 + quad * 8);
                    whh[g][kt] = ldfragW(Whh0 + (size_t)(g * 128 + gw * 16 + l15) * CTOT + kt * 32 + quad * 8);
                }
            float br[4], bz[4], bin_[4], bhn[4];
            {
                float4 a0 = *(const float4*)(bih0 + 0 * 128 + fb);
                float4 b0 = *(const float4*)(bhh0 + 0 * 128 + fb);
                float4 a1 = *(const float4*)(bih0 + 1 * 128 + fb);
                float4 b1 = *(const float4*)(bhh0 + 1 * 128 + fb);
                float4 a2 = *(const float4*)(bih0 + 2 * 128 + fb);
                float4 b2 = *(const float4*)(bhh0 + 2 * 128 + fb);
                br[0] = a0.x + b0.x; br[1] = a0.y + b0.y; br[2] = a0.z + b0.z; br[3] = a0.w + b0.w;
                bz[0] = a1.x + b1.x; bz[1] = a1.y + b1.y; bz[2] = a1.z + b1.z; bz[3] = a1.w + b1.w;
                bin_[0] = a2.x; bin_[1] = a2.y; bin_[2] = a2.z; bin_[3] = a2.w;
                bhn[0] = b2.x; bhn[1] = b2.y; bhn[2] = b2.z; bhn[3] = b2.w;
            }
            float h[4] = {0.f, 0.f, 0.f, 0.f};
            *(uint2*)&hb[0][l15][fb] = pack4(0.f, 0.f, 0.f, 0.f);
            __syncthreads();   // setup barrier (matched with producer path)

            int pg = 0;
#pragma unroll 1
            for (int T = 0; T <= 96; ++T) {
                if (T >= 1) {
                    const int t = T - 1;
                    asm volatile("s_waitcnt vmcnt(0)" ::: "memory");  // drain t-1 h1 store (6 bars old)
                    bf16x8_t ax[4], ah[4];
#pragma unroll
                    for (int kt = 0; kt < 4; ++kt) {
                        ax[kt] = ldfrag(&ybuf[(T - 1) & 1][l15][kt * 32 + quad * 8]);
                        ah[kt] = ldfrag(&hb[pg][l15][kt * 32 + quad * 8]);
                    }
                    f32x4_t gh[3], gx[3];
#pragma unroll
                    for (int g = 0; g < 3; ++g) {
                        gh[g] = (f32x4_t){0.f, 0.f, 0.f, 0.f};
                        gx[g] = (f32x4_t){0.f, 0.f, 0.f, 0.f};
                    }
#pragma unroll
                    for (int kt = 0; kt < 4; ++kt) {
                        gh[0] = mfma16(whh[0][kt], ah[kt], gh[0]);
                        gh[1] = mfma16(whh[1][kt], ah[kt], gh[1]);
                        gh[2] = mfma16(whh[2][kt], ah[kt], gh[2]);
                    }
#pragma unroll
                    for (int kt = 0; kt < 4; ++kt) {
                        gx[0] = mfma16(wih[0][kt], ax[kt], gx[0]);
                        gx[1] = mfma16(wih[1][kt], ax[kt], gx[1]);
                        gx[2] = mfma16(wih[2][kt], ax[kt], gx[2]);
                    }
#pragma unroll
                    for (int i = 0; i < 4; ++i) {
                        float rr = sigm(gx[0][i] + gh[0][i] + br[i]);
                        float zz = sigm(gx[1][i] + gh[1][i] + bz[i]);
                        float nn = tanh2((gx[2][i] + bin_[i]) + rr * (gh[2][i] + bhn[i]));
                        h[i] = nn + zz * (h[i] - nn);
                    }
                    uint2 pk = pack4(h[0], h[1], h[2], h[3]);
                    *(uint2*)&hb[pg ^ 1][l15][fb] = pk;
                    stg8(h1Traj + ((size_t)t * 1024 + row) * CTOT + fb, pk);
                    pg ^= 1;
                }
                LGKM_BAR();   // barrier 1 of 6
                // I1: release flag for t-1 (all gru0 waves drained their own
                // stores via vmcnt BEFORE the barrier above -> safe release)
                if (wv == 8 && lane == 0 && T >= 2)
                    __hip_atomic_store(&h1flag[c * 128 + (T - 2)], H1MAGIC(T - 2),
                                       __ATOMIC_RELAXED, __HIP_MEMORY_SCOPE_AGENT);
#pragma unroll
                for (int s = 1; s < 6; ++s) LGKM_BAR();   // barriers 2..6
            }
        }
        // common tail: all 16 waves
        asm volatile("s_waitcnt vmcnt(0)" ::: "memory");
        __syncthreads();
        if (wv == 8 && lane == 0)
            __hip_atomic_store(&h1flag[c * 128 + 95], H1MAGIC(95),
                               __ATOMIC_RELAXED, __HIP_MEMORY_SCOPE_AGENT);
        return;
    }

    // ================= Block B: GRU1 + MLP head (8 rider waves) ==============
    unsigned short (*zbuf)[16][134] = (unsigned short (*)[16][134])(smem);         // [2][16][134]
    unsigned short (*hidbuf)[72]    = (unsigned short (*)[72])(smem + 17152);      // [16][72]

    bf16x8_t wih[3][4], whh[3][4];
    float br[4], bz[4], bin_[4], bhn[4];
    if (wv < 8) {
#pragma unroll
        for (int g = 0; g < 3; ++g)
#pragma unroll
            for (int kt = 0; kt < 4; ++kt) {
                wih[g][kt] = ldfragW(Wih1 + (size_t)(g * 128 + gw * 16 + l15) * CTOT + kt * 32 + quad * 8);
                whh[g][kt] = ldfragW(Whh1 + (size_t)(g * 128 + gw * 16 + l15) * CTOT + kt * 32 + quad * 8);
            }
        float4 a0 = *(const float4*)(bih1 + 0 * 128 + fb);
        float4 b0 = *(const float4*)(bhh1 + 0 * 128 + fb);
        float4 a1 = *(const float4*)(bih1 + 1 * 128 + fb);
        float4 b1 = *(const float4*)(bhh1 + 1 * 128 + fb);
        float4 a2 = *(const float4*)(bih1 + 2 * 128 + fb);
        float4 b2 = *(const float4*)(bhh1 + 2 * 128 + fb);
        br[0] = a0.x + b0.x; br[1] = a0.y + b0.y; br[2] = a0.z + b0.z; br[3] = a0.w + b0.w;
        bz[0] = a1.x + b1.x; bz[1] = a1.y + b1.y; bz[2] = a1.z + b1.z; bz[3] = a1.w + b1.w;
        bin_[0] = a2.x; bin_[1] = a2.y; bin_[2] = a2.z; bin_[3] = a2.w;
        bhn[0] = b2.x; bhn[1] = b2.y; bhn[2] = b2.z; bhn[3] = b2.w;
    }
    float h[4] = {0.f, 0.f, 0.f, 0.f};
    if (wv < 8) *(uint2*)&zbuf[0][l15][fb] = pack4(0.f, 0.f, 0.f, 0.f);
    int p = 0;
    __syncthreads();

#pragma unroll 1
    for (int t = 0; t < TPTS; ++t) {
        waitflag(&h1flag[c * 128 + t], H1MAGIC(t));   // all 16 waves sync inside
        if (wv < 8) {
            const unsigned short* xp = h1Traj + ((size_t)t * 1024 + row) * CTOT;
            bf16x8_t ax[4], ah[4];
#pragma unroll
            for (int kt = 0; kt < 4; ++kt) ax[kt] = ldfragG(xp + kt * 32 + quad * 8);
#pragma unroll
            for (int kt = 0; kt < 4; ++kt)
                ah[kt] = ldfrag(&zbuf[p][l15][kt * 32 + quad * 8]);
            f32x4_t gh[3], gx[3];
#pragma unroll
            for (int g = 0; g < 3; ++g) {
                gh[g] = (f32x4_t){0.f, 0.f, 0.f, 0.f};
                gx[g] = (f32x4_t){0.f, 0.f, 0.f, 0.f};
            }
#pragma unroll
            for (int kt = 0; kt < 4; ++kt) {
                gh[0] = mfma16(whh[0][kt], ah[kt], gh[0]);
                gh[1] = mfma16(whh[1][kt], ah[kt], gh[1]);
                gh[2] = mfma16(whh[2][kt], ah[kt], gh[2]);
            }
#pragma unroll
            for (int kt = 0; kt < 4; ++kt) {
                gx[0] = mfma16(wih[0][kt], ax[kt], gx[0]);
                gx[1] = mfma16(wih[1][kt], ax[kt], gx[1]);
                gx[2] = mfma16(wih[2][kt], ax[kt], gx[2]);
            }
#pragma unroll
            for (int i = 0; i < 4; ++i) {
                float rr = sigm(gx[0][i] + gh[0][i] + br[i]);
                float zz = sigm(gx[1][i] + gh[1][i] + bz[i]);
                float nn = tanh2((gx[2][i] + bin_[i]) + rr * (gh[2][i] + bhn[i]));
                h[i] = nn + zz * (h[i] - nn);
            }
            *(uint2*)&zbuf[p ^ 1][l15][fb] = pack4(h[0], h[1], h[2], h[3]);
        }
        LGKM_BAR();
        p ^= 1;
    }

    // ---- MLP head ----
    if (wv < 4) {
        bf16x8_t wf[4], hf[4];
#pragma unroll
        for (int kt = 0; kt < 4; ++kt) {
            wf[kt] = ldfragW(W1v + (size_t)(wv * 16 + l15) * CTOT + kt * 32 + quad * 8);
            hf[kt] = ldfrag(&zbuf[p][l15][kt * 32 + quad * 8]);
        }
        f32x4_t acc = {0.f, 0.f, 0.f, 0.f};
#pragma unroll
        for (int kt = 0; kt < 4; ++kt) acc = mfma16(wf[kt], hf[kt], acc);
        float4 bb = *(const float4*)(b1v + wv * 16 + quad * 4);
        const float* bbp = (const float*)&bb;
        float gl[4];
#pragma unroll
        for (int i = 0; i < 4; ++i) {
            float x = acc[i] + bbp[i];
            gl[i] = 0.5f * x * (1.0f + erff(x * 0.70710678118654752f));
        }
        *(uint2*)&hidbuf[l15][wv * 16 + quad * 4] = pack4(gl[0], gl[1], gl[2], gl[3]);
    }
    __syncthreads();

    if (wv < 8) {
        bf16x8_t ahid[2];
#pragma unroll
        for (int kt = 0; kt < 2; ++kt)
            ahid[kt] = ldfrag(&hidbuf[l15][kt * 32 + quad * 8]);
#pragma unroll 1
        for (int j = 0; j < 24; ++j) {
            int mt2 = wv * 24 + j;
            bf16x8_t wf0 = ldfragW(W2v + (size_t)(mt2 * 16 + l15) * 64 + quad * 8);
            bf16x8_t wf1 = ldfragW(W2v + (size_t)(mt2 * 16 + l15) * 64 + 32 + quad * 8);
            float4 bv = *(const float4*)(b2v + mt2 * 16 + quad * 4);
            const float* bvp = (const float*)&bv;
            f32x4_t acc = {0.f, 0.f, 0.f, 0.f};
            acc = mfma16(wf0, ahid[0], acc);
            acc = mfma16(wf1, ahid[1], acc);
            float4 o;
            o.x = acc[0] + bvp[0]; o.y = acc[1] + bvp[1];
            o.z = acc[2] + bvp[2]; o.w = acc[3] + bvp[3];
            *(float4*)(outp + (size_t)row * 3072 + mt2 * 16 + quad * 4) = o;
        }
    }
#undef H1MAGIC
}

extern "C" void kernel_launch(void* const* d_in, const int* in_sizes, int n_in,
                              void* d_out, int out_size, void* d_ws, size_t ws_size,
                              hipStream_t stream) {
    // setup_inputs order: 0:x(unused) 1:yl 2:yh 3:W_ode 4:b_ode 5:W_ih0 6:W_hh0
    // 7:b_ih0 8:b_hh0 9:W_ih1 10:W_hh1 11:b_ih1 12:b_hh1 13:W1 14:b1 15:W2 16:b2
    const float* yl   = (const float*)d_in[1];
    const float* yh   = (const float*)d_in[2];
    const float* Wode = (const float*)d_in[3];
    const float* bode = (const float*)d_in[4];
    const float* Wih0 = (const float*)d_in[5];
    const float* Whh0 = (const float*)d_in[6];
    const float* bih0 = (const float*)d_in[7];
    const float* bhh0 = (const float*)d_in[8];
    const float* Wih1 = (const float*)d_in[9];
    const float* Whh1 = (const float*)d_in[10];
    const float* bih1 = (const float*)d_in[11];
    const float* bhh1 = (const float*)d_in[12];
    const float* W1v  = (const float*)d_in[13];
    const float* b1v  = (const float*)d_in[14];
    const float* W2v  = (const float*)d_in[15];
    const float* b2v  = (const float*)d_in[16];

    ode_forecaster<<<dim3(128), dim3(1024), 0, stream>>>(
        yl, yh, Wode, bode, Wih0, Whh0, bih0, bhh0,
        Wih1, Whh1, bih1, bhh1, W1v, b1v, W2v, b2v,
        (float*)d_out, (char*)d_ws);
}